// Round 8
// baseline (377.116 us; speedup 1.0000x reference)
//
#include <hip/hip_runtime.h>
#include <cstdint>

// B=4, T=4096, D=1024, H=16, d=64, C=64, N=T/C=64
#define B_ 4
#define T_ 4096
#define D_ 1024
#define H_ 16
#define HD_ 64
#define N_ 64

typedef __attribute__((ext_vector_type(8))) short s16x8;
typedef __attribute__((ext_vector_type(4))) float f32x4;

__device__ __forceinline__ unsigned short f2bf(float f) {
    unsigned int u = __builtin_bit_cast(unsigned int, f);
    u += 0x7fffu + ((u >> 16) & 1u);          // RNE
    return (unsigned short)(u >> 16);
}
__device__ __forceinline__ float bf2f(unsigned short h) {
    unsigned int u = ((unsigned int)h) << 16;
    return __builtin_bit_cast(float, u);
}
__device__ __forceinline__ void gl2lds(const short* g, short* l) {
    __builtin_amdgcn_global_load_lds(
        (const __attribute__((address_space(1))) void*)g,
        (__attribute__((address_space(3))) void*)l, 16, 0, 0);
}
#define MFMA16(a, b, c) __builtin_amdgcn_mfma_f32_16x16x32_bf16(a, b, c, 0, 0, 0)
#define SB0() __builtin_amdgcn_sched_barrier(0)
#define BAR() __builtin_amdgcn_s_barrier()

// ---------------------------------------------------------------------------
// Converters.
// ---------------------------------------------------------------------------
__global__ __launch_bounds__(256)
void k_cvt_split(const float* __restrict__ in, short* __restrict__ out, int n4)
{
    int i = blockIdx.x * blockDim.x + threadIdx.x;
    const int stride = gridDim.x * blockDim.x;
    for (; i < n4; i += stride) {
        float4 f = ((const float4*)in)[i];
        const float v[4] = {f.x, f.y, f.z, f.w};
        s16x8 o;
        #pragma unroll
        for (int j = 0; j < 4; ++j) {
            unsigned short h = f2bf(v[j]);
            o[j*2]   = (short)h;
            o[j*2+1] = (short)f2bf(v[j] - bf2f(h));
        }
        ((s16x8*)out)[i] = o;
    }
}
__global__ __launch_bounds__(256)
void k_cvt(const float* __restrict__ in, short* __restrict__ out, int n4)
{
    int i = blockIdx.x * blockDim.x + threadIdx.x;
    const int stride = gridDim.x * blockDim.x;
    for (; i < n4; i += stride) {
        float4 f = ((const float4*)in)[i];
        short4 o;
        o.x = (short)f2bf(f.x); o.y = (short)f2bf(f.y);
        o.z = (short)f2bf(f.z); o.w = (short)f2bf(f.w);
        *(short4*)(out + i * 4) = o;
    }
}

// ---------------------------------------------------------------------------
// bf16 MFMA GEMM, 8-phase schedule (m201 template port): O = A @ B^T.
// 256x256 tile, BK=64, 512 thr (8 waves 2x4), 16x16x32 MFMA.
// LDS [dbuf][mat][kk-half][256 rows x 32 cols] bf16 (64B rows) = 128 KiB.
// Staging unit = one (mat,kk) half = 2 gl2lds/wave (16 rows each).
// Per K-tile, 4 phases: {ds_read 8|4 frags; stage 1 half; SB; barrier;
// lgkm(0)+SB (rule 18); setprio(1); 16 MFMA; setprio(0); barrier}.
// Counted vmcnt(4) at end of ph1/ph3 retires exactly the halves the next
// two phases read (vmcnt(0) at ph1 of last tile). 2-4 halves in flight.
// Swizzle: phys 16B slot = rg ^ ((row>>1)&3); inverse pre-applied on the
// per-lane gl2lds source (both-sides rule). Uniform 2-way banks (free).
// MODE 0: k/v epilogue (sign bf16 -> Kb+KbT or VbT). MODE 1: fp32 Y.
// MODE 2: Q epilogue (bf16, *0.125).
// ---------------------------------------------------------------------------
template<int MODE, int KD, int NCB>
__global__ __launch_bounds__(512, 2)
void k_gemm(const short* __restrict__ A, const short* __restrict__ Bm,
            short* __restrict__ O1, short* __restrict__ O2,
            short* __restrict__ O3, float* __restrict__ Yf)
{
    __shared__ __align__(16) short LS[2][2][2][8192];  // [dbuf][mat][kk][256*32]

    const int tid = threadIdx.x;
    const int nwg = 64 * NCB;
    const int bid = blockIdx.x;
    const int sz  = (bid & 7) * (nwg >> 3) + (bid >> 3);   // XCD-contiguous
    const int cb  = sz % NCB, rb = sz / NCB;
    const int row0 = rb * 256, col0 = cb * 256;

    const int lane = tid & 63, w = tid >> 6;
    const int wr = w >> 2, wc = w & 3;
    const int cl = lane & 15, rg = lane >> 4;

    // per-lane pre-swizzled global source: lane -> row (lane>>2) of a 16-row
    // chunk, source slot (lane&3)^((lane>>3)&3)  (matches read swizzle).
    const int srow  = lane >> 2;
    const int sslot = (lane & 3) ^ ((lane >> 3) & 3);
    const short* gA = A  + (size_t)(row0 + w * 32 + srow) * KD + sslot * 8;
    const short* gB = Bm + (size_t)(col0 + w * 32 + srow) * KD + sslot * 8;

    f32x4 acc[8][4];
    #pragma unroll
    for (int i = 0; i < 8; ++i)
        #pragma unroll
        for (int j = 0; j < 4; ++j) acc[i][j] = (f32x4)0.f;

    // stage one (mat,kk) half of tile u: 2 gl2lds (16 rows each)
    auto stageH = [&](int mat, int kk, int u) {
        const short* g = mat ? gB : gA;
        const int off = u * 64 + kk * 32;
        short* dst = &LS[u & 1][mat][kk][(w * 32) * 32];
        gl2lds(g + off, dst);
        gl2lds(g + 16 * KD + off, dst + 16 * 32);
    };
    // swizzled fragment read: row R, logical slot rg, of [mat][kk] in buf pb
    auto ldf = [&](int pb, int mat, int kk, int R) -> s16x8 {
        const char* base = (const char*)&LS[pb][mat][kk][0];
        return *(const s16x8*)(base + R * 64 + ((rg ^ ((R >> 1) & 3)) << 4));
    };

    s16x8 fa[4], fb[4];
    auto rdA = [&](int pb, int kk, int mh) {
        #pragma unroll
        for (int mi = 0; mi < 4; ++mi)
            fa[mi] = ldf(pb, 0, kk, wr * 128 + mh * 64 + mi * 16 + cl);
    };
    auto rdB = [&](int pb, int kk) {
        #pragma unroll
        for (int ni = 0; ni < 4; ++ni)
            fb[ni] = ldf(pb, 1, kk, wc * 64 + ni * 16 + cl);
    };
    auto quad = [&](int mh) {
        __builtin_amdgcn_s_setprio(1);
        #pragma unroll
        for (int ni = 0; ni < 4; ++ni)
            #pragma unroll
            for (int mi = 0; mi < 4; ++mi)
                acc[mh * 4 + mi][ni] =
                    MFMA16(fa[mi], fb[ni], acc[mh * 4 + mi][ni]);
        __builtin_amdgcn_s_setprio(0);
    };

    const int nt = KD / 64;
    // prologue: all 4 halves of tile 0; wait for kh0 pair.
    stageH(0, 0, 0); stageH(1, 0, 0); stageH(0, 1, 0); stageH(1, 1, 0);
    asm volatile("s_waitcnt vmcnt(4)" ::: "memory");
    BAR();

    for (int t = 0; t < nt; ++t) {
        const int pb = t & 1;
        const bool st = (t + 1 < nt);
        // ---- phase 0: (mh0, kk0); stage A-kh0(t+1) ----
        rdB(pb, 0); rdA(pb, 0, 0);
        if (st) stageH(0, 0, t + 1);
        SB0(); BAR();
        asm volatile("s_waitcnt lgkmcnt(0)" ::: "memory"); SB0();
        quad(0);
        SB0(); BAR();
        // ---- phase 1: (mh1, kk0); stage B-kh0(t+1); vmcnt covers kk1(t) ----
        rdA(pb, 0, 1);
        if (st) stageH(1, 0, t + 1);
        SB0(); BAR();
        asm volatile("s_waitcnt lgkmcnt(0)" ::: "memory"); SB0();
        quad(1);
        SB0();
        if (st) asm volatile("s_waitcnt vmcnt(4)" ::: "memory");
        else    asm volatile("s_waitcnt vmcnt(0)" ::: "memory");
        BAR();
        // ---- phase 2: (mh0, kk1); stage A-kh1(t+1) ----
        rdB(pb, 1); rdA(pb, 1, 0);
        if (st) stageH(0, 1, t + 1);
        SB0(); BAR();
        asm volatile("s_waitcnt lgkmcnt(0)" ::: "memory"); SB0();
        quad(0);
        SB0(); BAR();
        // ---- phase 3: (mh1, kk1); stage B-kh1(t+1); vmcnt covers kh0(t+1) ----
        rdA(pb, 1, 1);
        if (st) stageH(1, 1, t + 1);
        SB0(); BAR();
        asm volatile("s_waitcnt lgkmcnt(0)" ::: "memory"); SB0();
        quad(1);
        SB0();
        asm volatile("s_waitcnt vmcnt(4)" ::: "memory");
        BAR();
    }

    const int m0 = row0 + wr * 128, n0 = col0 + wc * 64;
    if (MODE == 0) {
        const int s = 1 + (col0 >> 10);       // 1:k 2:v, uniform per block
        #pragma unroll
        for (int ni = 0; ni < 4; ++ni) {
            const int col = n0 + ni * 16 + cl;
            const int h = (col & 1023) >> 6, dd = col & 63;
            #pragma unroll
            for (int mi = 0; mi < 8; ++mi)
                #pragma unroll
                for (int r = 0; r < 4; ++r) {
                    const int bt = m0 + mi * 16 + rg * 4 + r;
                    const int bb = bt >> 12, t = bt & (T_ - 1);
                    const size_t bh64 = (size_t)(bb * H_ + h);
                    const short sg = (acc[mi][ni][r] >= 0.f) ? (short)0x3F80
                                                             : (short)0xBF80;
                    const size_t otr = bh64 * ((size_t)T_ * 64)
                                     + (size_t)(t >> 6) * 4096 + dd * 64 + (t & 63);
                    if (s == 1) {
                        O1[(bh64 * T_ + t) * 64 + dd] = sg;   // Kb [c][d]
                        O2[otr] = sg;                         // KbT [d][c]
                    } else {
                        O3[otr] = sg;                         // VbT [d][c]
                    }
                }
        }
    } else if (MODE == 2) {
        #pragma unroll
        for (int ni = 0; ni < 4; ++ni) {
            const int col = n0 + ni * 16 + cl;
            const int h = col >> 6, dd = col & 63;
            #pragma unroll
            for (int mi = 0; mi < 8; ++mi)
                #pragma unroll
                for (int r = 0; r < 4; ++r) {
                    const int bt = m0 + mi * 16 + rg * 4 + r;
                    const int bb = bt >> 12, t = bt & (T_ - 1);
                    O1[((size_t)(bb * H_ + h) * T_ + t) * 64 + dd] =
                        (short)f2bf(acc[mi][ni][r] * 0.125f);
                }
        }
    } else {
        #pragma unroll
        for (int ni = 0; ni < 4; ++ni) {
            const int col = n0 + ni * 16 + cl;
            #pragma unroll
            for (int mi = 0; mi < 8; ++mi)
                #pragma unroll
                for (int r = 0; r < 4; ++r)
                    Yf[(size_t)(m0 + mi * 16 + rg * 4 + r) * D_ + col] =
                        acc[mi][ni][r];
        }
    }
}

// ---------------------------------------------------------------------------
// K2 (MFMA): per chunk: S = mask(Q K^T); intra = S V^T-op -> OMi bf16;
// ckvT[dd][kd] = sum_c v[c][dd] k[c][kd] -> CKV8 int8 (exact small ints).
// ---------------------------------------------------------------------------
__global__ __launch_bounds__(256)
void k_chunk2(const short* __restrict__ Qb, const short* __restrict__ Kb,
              const short* __restrict__ KbT, const short* __restrict__ VbT,
              short* __restrict__ OMi, signed char* __restrict__ CKV8)
{
    __shared__ __align__(16) short Qs[4096], Ks[4096], KTs[4096], VTs[4096], Ss[4096];
    const int tid = threadIdx.x;
    const int bh = blockIdx.x >> 6, n = blockIdx.x & 63;
    const size_t cbase = ((size_t)bh * T_ + n * 64) * 64;

    auto stage_tile = [&](const short* g, short* l) {
        #pragma unroll
        for (int p = 0; p < 2; ++p) {
            const int off = tid * 16 + p * 4096;
            const int r = off >> 7;
            s16x8 v = *(const s16x8*)(g + (off >> 1));
            *(s16x8*)((char*)l + (off ^ ((r & 7) << 4))) = v;
        }
    };
    stage_tile(Qb  + cbase, Qs);
    stage_tile(Kb  + cbase, Ks);
    stage_tile(KbT + cbase, KTs);
    stage_tile(VbT + cbase, VTs);
    __syncthreads();

    const int lane = tid & 63, w = tid >> 6;
    const int cl = lane & 15, rg = lane >> 4;

    auto frag = [&](const short* l, int rowbase, int kk) -> s16x8 {
        const int row = rowbase + cl;
        int off = row * 128 + kk * 64 + rg * 16;
        off ^= (row & 7) << 4;
        return *(const s16x8*)((const char*)l + off);
    };

    // phase 1: S = Q K^T (masked), bf16 -> Ss
    {
        f32x4 a1[4];
        #pragma unroll
        for (int ni = 0; ni < 4; ++ni) a1[ni] = (f32x4)0.f;
        const s16x8 qa0 = frag(Qs, w * 16, 0), qa1 = frag(Qs, w * 16, 1);
        #pragma unroll
        for (int ni = 0; ni < 4; ++ni) {
            a1[ni] = MFMA16(qa0, frag(Ks, ni * 16, 0), a1[ni]);
            a1[ni] = MFMA16(qa1, frag(Ks, ni * 16, 1), a1[ni]);
        }
        #pragma unroll
        for (int ni = 0; ni < 4; ++ni)
            #pragma unroll
            for (int r = 0; r < 4; ++r) {
                const int i = w * 16 + rg * 4 + r, j = ni * 16 + cl;
                const float v = (j <= i) ? a1[ni][r] : 0.f;
                const int off = (i * 128 + j * 2) ^ ((i & 7) << 4);
                *(short*)((char*)Ss + off) = (short)f2bf(v);
            }
    }
    __syncthreads();

    // phase 2: intra = S * V; phase 3: ckvT[dd][kd]
    f32x4 a2[4], a3[4];
    #pragma unroll
    for (int ni = 0; ni < 4; ++ni) { a2[ni] = (f32x4)0.f; a3[ni] = (f32x4)0.f; }
    {
        const s16x8 sa0 = frag(Ss, w * 16, 0),  sa1 = frag(Ss, w * 16, 1);
        const s16x8 va0 = frag(VTs, w * 16, 0), va1 = frag(VTs, w * 16, 1);
        #pragma unroll
        for (int ni = 0; ni < 4; ++ni) {
            a2[ni] = MFMA16(sa0, frag(VTs, ni * 16, 0), a2[ni]);
            a2[ni] = MFMA16(sa1, frag(VTs, ni * 16, 1), a2[ni]);
            a3[ni] = MFMA16(va0, frag(KTs, ni * 16, 0), a3[ni]);
            a3[ni] = MFMA16(va1, frag(KTs, ni * 16, 1), a3[ni]);
        }
    }
    #pragma unroll
    for (int ni = 0; ni < 4; ++ni)
        #pragma unroll
        for (int r = 0; r < 4; ++r) {
            const int m = w * 16 + rg * 4 + r;     // i for intra, dd for ckv
            const int c = ni * 16 + cl;            // dd for intra, kd for ckv
            const int off = (m * 128 + c * 2) ^ ((m & 7) << 4);
            *(short*)((char*)Qs + off) = (short)f2bf(a2[ni][r]);
            ((signed char*)Ks)[m * 64 + c] = (signed char)(int)a3[ni][r];
        }
    __syncthreads();

    const int bb = bh >> 4, h = bh & 15;
    #pragma unroll
    for (int p = 0; p < 2; ++p) {
        const int off = tid * 16 + p * 4096;
        const int r = off >> 7;
        const int lo = off ^ ((r & 7) << 4);
        s16x8 v = *(const s16x8*)((char*)Qs + lo);
        const size_t gi = ((size_t)bb * T_ + n * 64 + r) * D_
                        + h * 64 + ((off & 127) >> 1);
        *(s16x8*)(OMi + gi) = v;
    }
    {
        const size_t c8 = ((size_t)bh * 64 + n) * 4096;
        *(int4*)(CKV8 + c8 + tid * 16) = *(const int4*)((const char*)Ks + tid * 16);
    }
}

// ---------------------------------------------------------------------------
// K3: integer exclusive scan of CKV8 over chunks -> PB bf16; FM fp32 exact.
// ---------------------------------------------------------------------------
__global__ __launch_bounds__(256)
void k_scan2(const signed char* __restrict__ CKV8, short* __restrict__ PB,
             float* __restrict__ FM, float* __restrict__ FC)
{
    const int bh = blockIdx.x >> 4;
    const int e  = (blockIdx.x & 15) * 256 + threadIdx.x;   // dd*64+kd
    const size_t b8 = (size_t)bh * N_ * 4096 + e;
    const size_t bp = (size_t)bh * N_ * 4096 + e;
    int run = 0;
    #pragma unroll
    for (int nn = 0; nn < 64; ++nn) {
        PB[bp + (size_t)nn * 4096] = (short)f2bf((float)run);
        run += (int)CKV8[b8 + (size_t)nn * 4096];
    }
    FM[(size_t)bh * 4096 + (e & 63) * 64 + (e >> 6)] = (float)run;
    if ((blockIdx.x & 15) == 0 && threadIdx.x == 0) FC[bh] = (float)T_;
}

// ---------------------------------------------------------------------------
// K4 (MFMA): cross = Q @ prefix; OMb = bf16((OMi + cross) / total).
// ---------------------------------------------------------------------------
__global__ __launch_bounds__(256)
void k_cross2(const short* __restrict__ Qb, const short* __restrict__ PB,
              const short* __restrict__ OMi, short* __restrict__ OMb)
{
    __shared__ __align__(16) short Qs[4096], Ps[4096], Cs[4096];
    const int tid = threadIdx.x;
    const int bh = blockIdx.x >> 6, n = blockIdx.x & 63;
    const size_t cbase = ((size_t)bh * T_ + n * 64) * 64;

    auto stage_tile = [&](const short* g, short* l) {
        #pragma unroll
        for (int p = 0; p < 2; ++p) {
            const int off = tid * 16 + p * 4096;
            const int r = off >> 7;
            s16x8 v = *(const s16x8*)(g + (off >> 1));
            *(s16x8*)((char*)l + (off ^ ((r & 7) << 4))) = v;
        }
    };
    stage_tile(Qb + cbase, Qs);
    stage_tile(PB + ((size_t)bh * 64 + n) * 4096, Ps);
    __syncthreads();

    const int lane = tid & 63, w = tid >> 6;
    const int cl = lane & 15, rg = lane >> 4;

    auto frag = [&](const short* l, int rowbase, int kk) -> s16x8 {
        const int row = rowbase + cl;
        int off = row * 128 + kk * 64 + rg * 16;
        off ^= (row & 7) << 4;
        return *(const s16x8*)((const char*)l + off);
    };

    f32x4 a1[4];
    #pragma unroll
    for (int ni = 0; ni < 4; ++ni) a1[ni] = (f32x4)0.f;
    const s16x8 qa0 = frag(Qs, w * 16, 0), qa1 = frag(Qs, w * 16, 1);
    #pragma unroll
    for (int ni = 0; ni < 4; ++ni) {
        a1[ni] = MFMA16(qa0, frag(Ps, ni * 16, 0), a1[ni]);
        a1[ni] = MFMA16(qa1, frag(Ps, ni * 16, 1), a1[ni]);
    }
    #pragma unroll
    for (int ni = 0; ni < 4; ++ni)
        #pragma unroll
        for (int r = 0; r < 4; ++r) {
            const int i = w * 16 + rg * 4 + r, j = ni * 16 + cl;
            const int off = (i * 128 + j * 2) ^ ((i & 7) << 4);
            *(short*)((char*)Cs + off) = (short)f2bf(a1[ni][r]);
        }
    __syncthreads();

    const int bb = bh >> 4, h = bh & 15;
    #pragma unroll
    for (int p = 0; p < 2; ++p) {
        const int off = tid * 16 + p * 4096;
        const int r = off >> 7;
        const int lo = off ^ ((r & 7) << 4);
        s16x8 cv = *(const s16x8*)((char*)Cs + lo);
        const size_t gi = ((size_t)bb * T_ + n * 64 + r) * D_
                        + h * 64 + ((off & 127) >> 1);
        s16x8 iv = *(const s16x8*)(OMi + gi);
        const float invt = 1.0f / (float)(n * 64 + r + 1);
        s16x8 ov;
        #pragma unroll
        for (int j = 0; j < 8; ++j) {
            const float f = (bf2f((unsigned short)iv[j])
                           + bf2f((unsigned short)cv[j])) * invt;
            ov[j] = (short)f2bf(f);
        }
        *(s16x8*)(OMb + gi) = ov;
    }
}

extern "C" void kernel_launch(void* const* d_in, const int* in_sizes, int n_in,
                              void* d_out, int out_size, void* d_ws, size_t ws_size,
                              hipStream_t stream)
{
    const float* X    = (const float*)d_in[0];
    const float* Wqkv = (const float*)d_in[1];
    const float* Wo   = (const float*)d_in[2];

    float* Y  = (float*)d_out;                       // [B,T,D]
    float* FM = Y + (size_t)B_ * T_ * D_;            // [B,H,64,64]
    float* FC = FM + (size_t)B_ * H_ * HD_ * HD_;    // [B,H,1,1]

    char* ws = (char*)d_ws;
    const size_t Mi = 1048576;
    short*       Qb   = (short*)(ws + 0 * Mi);     // 32 MiB
    short*       Kb   = (short*)(ws + 32 * Mi);    // 32 MiB
    short*       KbT  = (short*)(ws + 64 * Mi);    // 32 MiB (early)
    short*       PB   = (short*)(ws + 64 * Mi);    // 32 MiB (late, over KbT)
    short*       VbT  = (short*)(ws + 96 * Mi);    // 32 MiB
    short*       XS   = (short*)(ws + 128 * Mi);   // 64 MiB (early)
    short*       Xb   = (short*)(ws + 128 * Mi);   // 32 MiB (mid, over XS)
    short*       OMi  = (short*)(ws + 128 * Mi);   // 32 MiB (late, over Xb)
    short*       OMb  = (short*)(ws + 160 * Mi);   // 32 MiB
    short*       WSq  = (short*)(ws + 192 * Mi);   //  8 MiB (early)
    signed char* CKV8 = (signed char*)(ws + 192 * Mi); // 16 MiB (late)
    short*       Wqb  = (short*)(ws + 208 * Mi);   //  2 MiB
    short*       WoS  = (short*)(ws + 210 * Mi);   //  2 MiB
    if (ws_size < (size_t)222 * Mi) return;

    dim3 blk(256), blkg(512);
    // X (split) and W_kv (split, rows 1024..3071 of Wqkv)
    k_cvt_split<<<dim3(2048), blk, 0, stream>>>(X, XS, 4194304);
    k_cvt_split<<<dim3(1024), blk, 0, stream>>>(Wqkv + (size_t)1024 * 1024, WSq, 524288);
    // K/V GEMM: split K=2048, N=2048 (256^2 tiles, 8-phase)
    k_gemm<0, 2048, 8><<<dim3(512), blkg, 0, stream>>>(XS, WSq, Kb, KbT, VbT, nullptr);
    // Q GEMM: plain bf16 K=1024 (Xb overwrites XS after kv-GEMM done)
    k_cvt<<<dim3(2048), blk, 0, stream>>>(X, Xb, 4194304);
    k_cvt<<<dim3(512),  blk, 0, stream>>>(Wqkv, Wqb, 262144);
    k_gemm<2, 1024, 4><<<dim3(256), blkg, 0, stream>>>(Xb, Wqb, Qb, nullptr, nullptr, nullptr);
    // chunk-local MFMA work
    k_chunk2<<<dim3(4096), blk, 0, stream>>>(Qb, Kb, KbT, VbT, OMi, CKV8);
    k_scan2 <<<dim3(1024), blk, 0, stream>>>(CKV8, PB, FM, FC);
    k_cross2<<<dim3(4096), blk, 0, stream>>>(Qb, PB, OMi, OMb);
    // output GEMM
    k_cvt<<<dim3(512), blk, 0, stream>>>(Wo, WoS, 262144);
    k_gemm<1, 1024, 4><<<dim3(256), blkg, 0, stream>>>(OMb, WoS, nullptr, nullptr, nullptr, Y);
}

// Round 9
// 354.432 us; speedup vs baseline: 1.0640x; 1.0640x over previous
//
#include <hip/hip_runtime.h>
#include <cstdint>

// B=4, T=4096, D=1024, H=16, d=64, C=64, N=T/C=64
#define B_ 4
#define T_ 4096
#define D_ 1024
#define H_ 16
#define HD_ 64
#define N_ 64

typedef __attribute__((ext_vector_type(8))) short s16x8;
typedef __attribute__((ext_vector_type(4))) float f32x4;

__device__ __forceinline__ unsigned short f2bf(float f) {
    unsigned int u = __builtin_bit_cast(unsigned int, f);
    u += 0x7fffu + ((u >> 16) & 1u);          // RNE
    return (unsigned short)(u >> 16);
}
__device__ __forceinline__ float bf2f(unsigned short h) {
    unsigned int u = ((unsigned int)h) << 16;
    return __builtin_bit_cast(float, u);
}
__device__ __forceinline__ void gl2lds(const short* g, short* l) {
    __builtin_amdgcn_global_load_lds(
        (const __attribute__((address_space(1))) void*)g,
        (__attribute__((address_space(3))) void*)l, 16, 0, 0);
}
#define MFMA16(a, b, c) __builtin_amdgcn_mfma_f32_16x16x32_bf16(a, b, c, 0, 0, 0)
#define SB0() __builtin_amdgcn_sched_barrier(0)
#define BAR() __builtin_amdgcn_s_barrier()

// ---------------------------------------------------------------------------
// Converters. k_cvt_split: fp32 -> interleaved (hi,lo) bf16; optionally also
// emits the plain-bf16 (hi) copy in the same pass (saves a full re-read).
// ---------------------------------------------------------------------------
__global__ __launch_bounds__(256)
void k_cvt_split(const float* __restrict__ in, short* __restrict__ out,
                 short* __restrict__ out_hi, int n4)
{
    int i = blockIdx.x * blockDim.x + threadIdx.x;
    const int stride = gridDim.x * blockDim.x;
    for (; i < n4; i += stride) {
        float4 f = ((const float4*)in)[i];
        const float v[4] = {f.x, f.y, f.z, f.w};
        s16x8 o;
        short4 hi4;
        #pragma unroll
        for (int j = 0; j < 4; ++j) {
            unsigned short h = f2bf(v[j]);
            o[j*2]   = (short)h;
            o[j*2+1] = (short)f2bf(v[j] - bf2f(h));
            ((short*)&hi4)[j] = (short)h;
        }
        ((s16x8*)out)[i] = o;
        if (out_hi) *(short4*)(out_hi + i * 4) = hi4;
    }
}
__global__ __launch_bounds__(256)
void k_cvt(const float* __restrict__ in, short* __restrict__ out, int n4)
{
    int i = blockIdx.x * blockDim.x + threadIdx.x;
    const int stride = gridDim.x * blockDim.x;
    for (; i < n4; i += stride) {
        float4 f = ((const float4*)in)[i];
        short4 o;
        o.x = (short)f2bf(f.x); o.y = (short)f2bf(f.y);
        o.z = (short)f2bf(f.z); o.w = (short)f2bf(f.w);
        *(short4*)(out + i * 4) = o;
    }
}

// ---------------------------------------------------------------------------
// bf16 MFMA GEMM, 8-phase schedule (r8 structure, frozen): O = A @ B^T.
// 256x256 tile, BK=64, 512 thr (8 waves 2x4), 16x16x32 MFMA.
// LDS [dbuf][mat][kk-half][256x32] bf16; staging unit = one (mat,kk) half.
// Counted vmcnt(4) at ph1/ph3 ends; lgkm(0)+SB fence per phase; setprio on
// MFMA clusters; swizzle slot = rg ^ ((row>>1)&3) with pre-swizzled source.
// MODE 0: k/v epilogue (sign bf16 -> Kb [c][d] or VbT [d][c]). MODE 1: fp32 Y.
// MODE 2: Q epilogue (bf16, *0.125).
// ---------------------------------------------------------------------------
template<int MODE, int KD, int NCB>
__global__ __launch_bounds__(512, 2)
void k_gemm(const short* __restrict__ A, const short* __restrict__ Bm,
            short* __restrict__ O1, short* __restrict__ O3,
            float* __restrict__ Yf)
{
    __shared__ __align__(16) short LS[2][2][2][8192];  // [dbuf][mat][kk][256*32]

    const int tid = threadIdx.x;
    const int nwg = 64 * NCB;
    const int bid = blockIdx.x;
    const int sz  = (bid & 7) * (nwg >> 3) + (bid >> 3);   // XCD-contiguous
    const int cb  = sz % NCB, rb = sz / NCB;
    const int row0 = rb * 256, col0 = cb * 256;

    const int lane = tid & 63, w = tid >> 6;
    const int wr = w >> 2, wc = w & 3;
    const int cl = lane & 15, rg = lane >> 4;

    const int srow  = lane >> 2;
    const int sslot = (lane & 3) ^ ((lane >> 3) & 3);
    const short* gA = A  + (size_t)(row0 + w * 32 + srow) * KD + sslot * 8;
    const short* gB = Bm + (size_t)(col0 + w * 32 + srow) * KD + sslot * 8;

    f32x4 acc[8][4];
    #pragma unroll
    for (int i = 0; i < 8; ++i)
        #pragma unroll
        for (int j = 0; j < 4; ++j) acc[i][j] = (f32x4)0.f;

    auto stageH = [&](int mat, int kk, int u) {
        const short* g = mat ? gB : gA;
        const int off = u * 64 + kk * 32;
        short* dst = &LS[u & 1][mat][kk][(w * 32) * 32];
        gl2lds(g + off, dst);
        gl2lds(g + 16 * KD + off, dst + 16 * 32);
    };
    auto ldf = [&](int pb, int mat, int kk, int R) -> s16x8 {
        const char* base = (const char*)&LS[pb][mat][kk][0];
        return *(const s16x8*)(base + R * 64 + ((rg ^ ((R >> 1) & 3)) << 4));
    };

    s16x8 fa[4], fb[4];
    auto rdA = [&](int pb, int kk, int mh) {
        #pragma unroll
        for (int mi = 0; mi < 4; ++mi)
            fa[mi] = ldf(pb, 0, kk, wr * 128 + mh * 64 + mi * 16 + cl);
    };
    auto rdB = [&](int pb, int kk) {
        #pragma unroll
        for (int ni = 0; ni < 4; ++ni)
            fb[ni] = ldf(pb, 1, kk, wc * 64 + ni * 16 + cl);
    };
    auto quad = [&](int mh) {
        __builtin_amdgcn_s_setprio(1);
        #pragma unroll
        for (int ni = 0; ni < 4; ++ni)
            #pragma unroll
            for (int mi = 0; mi < 4; ++mi)
                acc[mh * 4 + mi][ni] =
                    MFMA16(fa[mi], fb[ni], acc[mh * 4 + mi][ni]);
        __builtin_amdgcn_s_setprio(0);
    };

    const int nt = KD / 64;
    stageH(0, 0, 0); stageH(1, 0, 0); stageH(0, 1, 0); stageH(1, 1, 0);
    asm volatile("s_waitcnt vmcnt(4)" ::: "memory");
    BAR();

    for (int t = 0; t < nt; ++t) {
        const int pb = t & 1;
        const bool st = (t + 1 < nt);
        // ---- phase 0: (mh0, kk0); stage A-kh0(t+1) ----
        rdB(pb, 0); rdA(pb, 0, 0);
        if (st) stageH(0, 0, t + 1);
        SB0(); BAR();
        asm volatile("s_waitcnt lgkmcnt(0)" ::: "memory"); SB0();
        quad(0);
        SB0(); BAR();
        // ---- phase 1: (mh1, kk0); stage B-kh0(t+1); vmcnt covers kk1(t) ----
        rdA(pb, 0, 1);
        if (st) stageH(1, 0, t + 1);
        SB0(); BAR();
        asm volatile("s_waitcnt lgkmcnt(0)" ::: "memory"); SB0();
        quad(1);
        SB0();
        if (st) asm volatile("s_waitcnt vmcnt(4)" ::: "memory");
        else    asm volatile("s_waitcnt vmcnt(0)" ::: "memory");
        BAR();
        // ---- phase 2: (mh0, kk1); stage A-kh1(t+1) ----
        rdB(pb, 1); rdA(pb, 1, 0);
        if (st) stageH(0, 1, t + 1);
        SB0(); BAR();
        asm volatile("s_waitcnt lgkmcnt(0)" ::: "memory"); SB0();
        quad(0);
        SB0(); BAR();
        // ---- phase 3: (mh1, kk1); stage B-kh1(t+1); vmcnt covers kh0(t+1) ----
        rdA(pb, 1, 1);
        if (st) stageH(1, 1, t + 1);
        SB0(); BAR();
        asm volatile("s_waitcnt lgkmcnt(0)" ::: "memory"); SB0();
        quad(1);
        SB0();
        asm volatile("s_waitcnt vmcnt(4)" ::: "memory");
        BAR();
    }

    const int m0 = row0 + wr * 128, n0 = col0 + wc * 64;
    if (MODE == 0) {
        const int s = 1 + (col0 >> 10);       // 1:k 2:v, uniform per block
        #pragma unroll
        for (int ni = 0; ni < 4; ++ni) {
            const int col = n0 + ni * 16 + cl;
            const int h = (col & 1023) >> 6, dd = col & 63;
            #pragma unroll
            for (int mi = 0; mi < 8; ++mi)
                #pragma unroll
                for (int r = 0; r < 4; ++r) {
                    const int bt = m0 + mi * 16 + rg * 4 + r;
                    const int bb = bt >> 12, t = bt & (T_ - 1);
                    const size_t bh64 = (size_t)(bb * H_ + h);
                    const short sg = (acc[mi][ni][r] >= 0.f) ? (short)0x3F80
                                                             : (short)0xBF80;
                    if (s == 1) {
                        O1[(bh64 * T_ + t) * 64 + dd] = sg;   // Kb [c][d]
                    } else {
                        const size_t otr = bh64 * ((size_t)T_ * 64)
                                         + (size_t)(t >> 6) * 4096 + dd * 64 + (t & 63);
                        O3[otr] = sg;                         // VbT [d][c]
                    }
                }
        }
    } else if (MODE == 2) {
        #pragma unroll
        for (int ni = 0; ni < 4; ++ni) {
            const int col = n0 + ni * 16 + cl;
            const int h = col >> 6, dd = col & 63;
            #pragma unroll
            for (int mi = 0; mi < 8; ++mi)
                #pragma unroll
                for (int r = 0; r < 4; ++r) {
                    const int bt = m0 + mi * 16 + rg * 4 + r;
                    const int bb = bt >> 12, t = bt & (T_ - 1);
                    O1[((size_t)(bb * H_ + h) * T_ + t) * 64 + dd] =
                        (short)f2bf(acc[mi][ni][r] * 0.125f);
                }
        }
    } else {
        #pragma unroll
        for (int ni = 0; ni < 4; ++ni) {
            const int col = n0 + ni * 16 + cl;
            #pragma unroll
            for (int mi = 0; mi < 8; ++mi)
                #pragma unroll
                for (int r = 0; r < 4; ++r)
                    Yf[(size_t)(m0 + mi * 16 + rg * 4 + r) * D_ + col] =
                        acc[mi][ni][r];
        }
    }
}

// ---------------------------------------------------------------------------
// K2 (MFMA): per chunk: S = mask(Q K^T); intra = S V^T-op -> OMi bf16;
// ckvT[dd][kd] = sum_c v[c][dd] k[c][kd] -> CKV8 int8 (exact small ints).
// KTs built in-LDS from the staged Kb tile (no KbT global array).
// ---------------------------------------------------------------------------
__global__ __launch_bounds__(256)
void k_chunk2(const short* __restrict__ Qb, const short* __restrict__ Kb,
              const short* __restrict__ VbT,
              short* __restrict__ OMi, signed char* __restrict__ CKV8)
{
    __shared__ __align__(16) short Qs[4096], Ks[4096], KTs[4096], VTs[4096], Ss[4096];
    const int tid = threadIdx.x;
    const int bh = blockIdx.x >> 6, n = blockIdx.x & 63;
    const size_t cbase = ((size_t)bh * T_ + n * 64) * 64;

    auto stage_tile = [&](const short* g, short* l) {
        #pragma unroll
        for (int p = 0; p < 2; ++p) {
            const int off = tid * 16 + p * 4096;
            const int r = off >> 7;
            s16x8 v = *(const s16x8*)(g + (off >> 1));
            *(s16x8*)((char*)l + (off ^ ((r & 7) << 4))) = v;
        }
    };
    stage_tile(Qb  + cbase, Qs);
    stage_tile(VbT + cbase, VTs);
    // K: stage Ks and scatter the transpose into KTs in the same pass.
    #pragma unroll
    for (int p = 0; p < 2; ++p) {
        const int off = tid * 16 + p * 4096;
        const int r  = off >> 7;            // chunk row c
        const int c0 = (off & 127) >> 1;    // first d col (mult of 8)
        s16x8 v = *(const s16x8*)(Kb + cbase + (off >> 1));
        *(s16x8*)((char*)Ks + (off ^ ((r & 7) << 4))) = v;
        #pragma unroll
        for (int j = 0; j < 8; ++j) {
            const int off2 = ((c0 + j) * 128 + r * 2) ^ (((c0 + j) & 7) << 4);
            *(short*)((char*)KTs + off2) = v[j];
        }
    }
    __syncthreads();

    const int lane = tid & 63, w = tid >> 6;
    const int cl = lane & 15, rg = lane >> 4;

    auto frag = [&](const short* l, int rowbase, int kk) -> s16x8 {
        const int row = rowbase + cl;
        int off = row * 128 + kk * 64 + rg * 16;
        off ^= (row & 7) << 4;
        return *(const s16x8*)((const char*)l + off);
    };

    // phase 1: S = Q K^T (masked), bf16 -> Ss
    {
        f32x4 a1[4];
        #pragma unroll
        for (int ni = 0; ni < 4; ++ni) a1[ni] = (f32x4)0.f;
        const s16x8 qa0 = frag(Qs, w * 16, 0), qa1 = frag(Qs, w * 16, 1);
        #pragma unroll
        for (int ni = 0; ni < 4; ++ni) {
            a1[ni] = MFMA16(qa0, frag(Ks, ni * 16, 0), a1[ni]);
            a1[ni] = MFMA16(qa1, frag(Ks, ni * 16, 1), a1[ni]);
        }
        #pragma unroll
        for (int ni = 0; ni < 4; ++ni)
            #pragma unroll
            for (int r = 0; r < 4; ++r) {
                const int i = w * 16 + rg * 4 + r, j = ni * 16 + cl;
                const float v = (j <= i) ? a1[ni][r] : 0.f;
                const int off = (i * 128 + j * 2) ^ ((i & 7) << 4);
                *(short*)((char*)Ss + off) = (short)f2bf(v);
            }
    }
    __syncthreads();

    // phase 2: intra = S * V; phase 3: ckvT[dd][kd]
    f32x4 a2[4], a3[4];
    #pragma unroll
    for (int ni = 0; ni < 4; ++ni) { a2[ni] = (f32x4)0.f; a3[ni] = (f32x4)0.f; }
    {
        const s16x8 sa0 = frag(Ss, w * 16, 0),  sa1 = frag(Ss, w * 16, 1);
        const s16x8 va0 = frag(VTs, w * 16, 0), va1 = frag(VTs, w * 16, 1);
        #pragma unroll
        for (int ni = 0; ni < 4; ++ni) {
            a2[ni] = MFMA16(sa0, frag(VTs, ni * 16, 0), a2[ni]);
            a2[ni] = MFMA16(sa1, frag(VTs, ni * 16, 1), a2[ni]);
            a3[ni] = MFMA16(va0, frag(KTs, ni * 16, 0), a3[ni]);
            a3[ni] = MFMA16(va1, frag(KTs, ni * 16, 1), a3[ni]);
        }
    }
    #pragma unroll
    for (int ni = 0; ni < 4; ++ni)
        #pragma unroll
        for (int r = 0; r < 4; ++r) {
            const int m = w * 16 + rg * 4 + r;     // i for intra, dd for ckv
            const int c = ni * 16 + cl;            // dd for intra, kd for ckv
            const int off = (m * 128 + c * 2) ^ ((m & 7) << 4);
            *(short*)((char*)Qs + off) = (short)f2bf(a2[ni][r]);
            ((signed char*)Ks)[m * 64 + c] = (signed char)(int)a3[ni][r];
        }
    __syncthreads();

    const int bb = bh >> 4, h = bh & 15;
    #pragma unroll
    for (int p = 0; p < 2; ++p) {
        const int off = tid * 16 + p * 4096;
        const int r = off >> 7;
        const int lo = off ^ ((r & 7) << 4);
        s16x8 v = *(const s16x8*)((char*)Qs + lo);
        const size_t gi = ((size_t)bb * T_ + n * 64 + r) * D_
                        + h * 64 + ((off & 127) >> 1);
        *(s16x8*)(OMi + gi) = v;
    }
    {
        const size_t c8 = ((size_t)bh * 64 + n) * 4096;
        *(int4*)(CKV8 + c8 + tid * 16) = *(const int4*)((const char*)Ks + tid * 16);
    }
}

// ---------------------------------------------------------------------------
// K3: integer exclusive scan of CKV8 over chunks -> PB bf16; FM fp32 exact.
// ---------------------------------------------------------------------------
__global__ __launch_bounds__(256)
void k_scan2(const signed char* __restrict__ CKV8, short* __restrict__ PB,
             float* __restrict__ FM, float* __restrict__ FC)
{
    const int bh = blockIdx.x >> 4;
    const int e  = (blockIdx.x & 15) * 256 + threadIdx.x;   // dd*64+kd
    const size_t b8 = (size_t)bh * N_ * 4096 + e;
    const size_t bp = (size_t)bh * N_ * 4096 + e;
    int run = 0;
    #pragma unroll
    for (int nn = 0; nn < 64; ++nn) {
        PB[bp + (size_t)nn * 4096] = (short)f2bf((float)run);
        run += (int)CKV8[b8 + (size_t)nn * 4096];
    }
    FM[(size_t)bh * 4096 + (e & 63) * 64 + (e >> 6)] = (float)run;
    if ((blockIdx.x & 15) == 0 && threadIdx.x == 0) FC[bh] = (float)T_;
}

// ---------------------------------------------------------------------------
// K4 (MFMA): cross = Q @ prefix; OMb = bf16((OMi + cross) / total).
// ---------------------------------------------------------------------------
__global__ __launch_bounds__(256)
void k_cross2(const short* __restrict__ Qb, const short* __restrict__ PB,
              const short* __restrict__ OMi, short* __restrict__ OMb)
{
    __shared__ __align__(16) short Qs[4096], Ps[4096], Cs[4096];
    const int tid = threadIdx.x;
    const int bh = blockIdx.x >> 6, n = blockIdx.x & 63;
    const size_t cbase = ((size_t)bh * T_ + n * 64) * 64;

    auto stage_tile = [&](const short* g, short* l) {
        #pragma unroll
        for (int p = 0; p < 2; ++p) {
            const int off = tid * 16 + p * 4096;
            const int r = off >> 7;
            s16x8 v = *(const s16x8*)(g + (off >> 1));
            *(s16x8*)((char*)l + (off ^ ((r & 7) << 4))) = v;
        }
    };
    stage_tile(Qb + cbase, Qs);
    stage_tile(PB + ((size_t)bh * 64 + n) * 4096, Ps);
    __syncthreads();

    const int lane = tid & 63, w = tid >> 6;
    const int cl = lane & 15, rg = lane >> 4;

    auto frag = [&](const short* l, int rowbase, int kk) -> s16x8 {
        const int row = rowbase + cl;
        int off = row * 128 + kk * 64 + rg * 16;
        off ^= (row & 7) << 4;
        return *(const s16x8*)((const char*)l + off);
    };

    f32x4 a1[4];
    #pragma unroll
    for (int ni = 0; ni < 4; ++ni) a1[ni] = (f32x4)0.f;
    const s16x8 qa0 = frag(Qs, w * 16, 0), qa1 = frag(Qs, w * 16, 1);
    #pragma unroll
    for (int ni = 0; ni < 4; ++ni) {
        a1[ni] = MFMA16(qa0, frag(Ps, ni * 16, 0), a1[ni]);
        a1[ni] = MFMA16(qa1, frag(Ps, ni * 16, 1), a1[ni]);
    }
    #pragma unroll
    for (int ni = 0; ni < 4; ++ni)
        #pragma unroll
        for (int r = 0; r < 4; ++r) {
            const int i = w * 16 + rg * 4 + r, j = ni * 16 + cl;
            const int off = (i * 128 + j * 2) ^ ((i & 7) << 4);
            *(short*)((char*)Cs + off) = (short)f2bf(a1[ni][r]);
        }
    __syncthreads();

    const int bb = bh >> 4, h = bh & 15;
    #pragma unroll
    for (int p = 0; p < 2; ++p) {
        const int off = tid * 16 + p * 4096;
        const int r = off >> 7;
        const int lo = off ^ ((r & 7) << 4);
        s16x8 cv = *(const s16x8*)((char*)Cs + lo);
        const size_t gi = ((size_t)bb * T_ + n * 64 + r) * D_
                        + h * 64 + ((off & 127) >> 1);
        s16x8 iv = *(const s16x8*)(OMi + gi);
        const float invt = 1.0f / (float)(n * 64 + r + 1);
        s16x8 ov;
        #pragma unroll
        for (int j = 0; j < 8; ++j) {
            const float f = (bf2f((unsigned short)iv[j])
                           + bf2f((unsigned short)cv[j])) * invt;
            ov[j] = (short)f2bf(f);
        }
        *(s16x8*)(OMb + gi) = ov;
    }
}

extern "C" void kernel_launch(void* const* d_in, const int* in_sizes, int n_in,
                              void* d_out, int out_size, void* d_ws, size_t ws_size,
                              hipStream_t stream)
{
    const float* X    = (const float*)d_in[0];
    const float* Wqkv = (const float*)d_in[1];
    const float* Wo   = (const float*)d_in[2];

    float* Y  = (float*)d_out;                       // [B,T,D]
    float* FM = Y + (size_t)B_ * T_ * D_;            // [B,H,64,64]
    float* FC = FM + (size_t)B_ * H_ * HD_ * HD_;    // [B,H,1,1]

    char* ws = (char*)d_ws;
    const size_t Mi = 1048576;
    // Timeline: cvt_split X -> {XS@128, Xb@32}; cvt Wq -> Wqb@208;
    // Q-gemm (Xb,Wqb -> Qb@0); cvt_split Wkv -> WSq@192;
    // KV-gemm (XS,WSq -> Kb@32 over dead Xb, VbT@96);
    // chunk2 (Qb,Kb,VbT -> OMi@128 over dead XS, CKV8@192 over dead WSq);
    // scan2 -> PB@64; cross2 -> OMb@160; cvt Wo -> WoS@210; out-gemm -> Y.
    short*       Qb   = (short*)(ws + 0 * Mi);     // 32 MiB
    short*       Xb   = (short*)(ws + 32 * Mi);    // 32 MiB (early)
    short*       Kb   = (short*)(ws + 32 * Mi);    // 32 MiB (late, over Xb)
    short*       PB   = (short*)(ws + 64 * Mi);    // 32 MiB
    short*       VbT  = (short*)(ws + 96 * Mi);    // 32 MiB
    short*       XS   = (short*)(ws + 128 * Mi);   // 64 MiB (early)
    short*       OMi  = (short*)(ws + 128 * Mi);   // 32 MiB (late, over XS)
    short*       OMb  = (short*)(ws + 160 * Mi);   // 32 MiB (late, over XS hi)
    short*       WSq  = (short*)(ws + 192 * Mi);   //  8 MiB (early)
    signed char* CKV8 = (signed char*)(ws + 192 * Mi); // 16 MiB (late)
    short*       Wqb  = (short*)(ws + 208 * Mi);   //  2 MiB
    short*       WoS  = (short*)(ws + 210 * Mi);   //  2 MiB
    if (ws_size < (size_t)222 * Mi) return;

    dim3 blk(256), blkg(512);
    // X: split (XS) + hi copy (Xb) in one pass
    k_cvt_split<<<dim3(2048), blk, 0, stream>>>(X, XS, Xb, 4194304);
    // Q GEMM first (Xb consumed before Kb overwrites it)
    k_cvt<<<dim3(512), blk, 0, stream>>>(Wqkv, Wqb, 262144);
    k_gemm<2, 1024, 4><<<dim3(256), blkg, 0, stream>>>(Xb, Wqb, Qb, nullptr, nullptr);
    // K/V GEMM: split K=2048, N=2048
    k_cvt_split<<<dim3(1024), blk, 0, stream>>>(Wqkv + (size_t)1024 * 1024, WSq, nullptr, 524288);
    k_gemm<0, 2048, 8><<<dim3(512), blkg, 0, stream>>>(XS, WSq, Kb, VbT, nullptr);
    // chunk-local MFMA work (K-transpose built in LDS)
    k_chunk2<<<dim3(4096), blk, 0, stream>>>(Qb, Kb, VbT, OMi, CKV8);
    k_scan2 <<<dim3(1024), blk, 0, stream>>>(CKV8, PB, FM, FC);
    k_cross2<<<dim3(4096), blk, 0, stream>>>(Qb, PB, OMi, OMb);
    // output GEMM
    k_cvt<<<dim3(512), blk, 0, stream>>>(Wo, WoS, 262144);
    k_gemm<1, 1024, 4><<<dim3(256), blkg, 0, stream>>>(OMb, WoS, nullptr, nullptr, Y);
}

// Round 10
// 337.701 us; speedup vs baseline: 1.1167x; 1.0495x over previous
//
#include <hip/hip_runtime.h>
#include <cstdint>

// B=4, T=4096, D=1024, H=16, d=64, C=64, N=T/C=64
#define B_ 4
#define T_ 4096
#define D_ 1024
#define H_ 16
#define HD_ 64
#define N_ 64

typedef __attribute__((ext_vector_type(8))) short s16x8;
typedef __attribute__((ext_vector_type(4))) float f32x4;

__device__ __forceinline__ unsigned short f2bf(float f) {
    unsigned int u = __builtin_bit_cast(unsigned int, f);
    u += 0x7fffu + ((u >> 16) & 1u);          // RNE
    return (unsigned short)(u >> 16);
}
__device__ __forceinline__ float bf2f(unsigned short h) {
    unsigned int u = ((unsigned int)h) << 16;
    return __builtin_bit_cast(float, u);
}
__device__ __forceinline__ void gl2lds(const short* g, short* l) {
    __builtin_amdgcn_global_load_lds(
        (const __attribute__((address_space(1))) void*)g,
        (__attribute__((address_space(3))) void*)l, 16, 0, 0);
}
#define MFMA16(a, b, c) __builtin_amdgcn_mfma_f32_16x16x32_bf16(a, b, c, 0, 0, 0)
#define SB0() __builtin_amdgcn_sched_barrier(0)
#define BAR() __builtin_amdgcn_s_barrier()

#define BF_P1 ((short)0x3F80)
#define BF_M1 ((short)0xBF80)

// ---------------------------------------------------------------------------
// Converters. k_cvt_split: fp32 -> interleaved (hi,lo) bf16; optionally also
// emits the plain-bf16 (hi) copy in the same pass.
// ---------------------------------------------------------------------------
__global__ __launch_bounds__(256)
void k_cvt_split(const float* __restrict__ in, short* __restrict__ out,
                 short* __restrict__ out_hi, int n4)
{
    int i = blockIdx.x * blockDim.x + threadIdx.x;
    const int stride = gridDim.x * blockDim.x;
    for (; i < n4; i += stride) {
        float4 f = ((const float4*)in)[i];
        const float v[4] = {f.x, f.y, f.z, f.w};
        s16x8 o;
        short4 hi4;
        #pragma unroll
        for (int j = 0; j < 4; ++j) {
            unsigned short h = f2bf(v[j]);
            o[j*2]   = (short)h;
            o[j*2+1] = (short)f2bf(v[j] - bf2f(h));
            ((short*)&hi4)[j] = (short)h;
        }
        ((s16x8*)out)[i] = o;
        if (out_hi) *(short4*)(out_hi + i * 4) = hi4;
    }
}
__global__ __launch_bounds__(256)
void k_cvt(const float* __restrict__ in, short* __restrict__ out, int n4)
{
    int i = blockIdx.x * blockDim.x + threadIdx.x;
    const int stride = gridDim.x * blockDim.x;
    for (; i < n4; i += stride) {
        float4 f = ((const float4*)in)[i];
        short4 o;
        o.x = (short)f2bf(f.x); o.y = (short)f2bf(f.y);
        o.z = (short)f2bf(f.z); o.w = (short)f2bf(f.w);
        *(short4*)(out + i * 4) = o;
    }
}

// ---------------------------------------------------------------------------
// bf16 MFMA GEMM, 8-phase schedule (frozen r8/r9 structure): O = A @ B^T.
// 256x256 tile, BK=64, 512 thr (8 waves 2x4), 16x16x32 MFMA.
// MODE 0: k/v epilogue (sign INT8 -> Kb8 [c][d] / VbT8 [d][c]).
// MODE 1: fp32 Y.  MODE 2: Q epilogue (bf16, *0.125).
// ---------------------------------------------------------------------------
template<int MODE, int KD, int NCB>
__global__ __launch_bounds__(512, 2)
void k_gemm(const short* __restrict__ A, const short* __restrict__ Bm,
            short* __restrict__ Oq, signed char* __restrict__ K8,
            signed char* __restrict__ V8, float* __restrict__ Yf)
{
    __shared__ __align__(16) short LS[2][2][2][8192];  // [dbuf][mat][kk][256*32]

    const int tid = threadIdx.x;
    const int nwg = 64 * NCB;
    const int bid = blockIdx.x;
    const int sz  = (bid & 7) * (nwg >> 3) + (bid >> 3);   // XCD-contiguous
    const int cb  = sz % NCB, rb = sz / NCB;
    const int row0 = rb * 256, col0 = cb * 256;

    const int lane = tid & 63, w = tid >> 6;
    const int wr = w >> 2, wc = w & 3;
    const int cl = lane & 15, rg = lane >> 4;

    const int srow  = lane >> 2;
    const int sslot = (lane & 3) ^ ((lane >> 3) & 3);
    const short* gA = A  + (size_t)(row0 + w * 32 + srow) * KD + sslot * 8;
    const short* gB = Bm + (size_t)(col0 + w * 32 + srow) * KD + sslot * 8;

    f32x4 acc[8][4];
    #pragma unroll
    for (int i = 0; i < 8; ++i)
        #pragma unroll
        for (int j = 0; j < 4; ++j) acc[i][j] = (f32x4)0.f;

    auto stageH = [&](int mat, int kk, int u) {
        const short* g = mat ? gB : gA;
        const int off = u * 64 + kk * 32;
        short* dst = &LS[u & 1][mat][kk][(w * 32) * 32];
        gl2lds(g + off, dst);
        gl2lds(g + 16 * KD + off, dst + 16 * 32);
    };
    auto ldf = [&](int pb, int mat, int kk, int R) -> s16x8 {
        const char* base = (const char*)&LS[pb][mat][kk][0];
        return *(const s16x8*)(base + R * 64 + ((rg ^ ((R >> 1) & 3)) << 4));
    };

    s16x8 fa[4], fb[4];
    auto rdA = [&](int pb, int kk, int mh) {
        #pragma unroll
        for (int mi = 0; mi < 4; ++mi)
            fa[mi] = ldf(pb, 0, kk, wr * 128 + mh * 64 + mi * 16 + cl);
    };
    auto rdB = [&](int pb, int kk) {
        #pragma unroll
        for (int ni = 0; ni < 4; ++ni)
            fb[ni] = ldf(pb, 1, kk, wc * 64 + ni * 16 + cl);
    };
    auto quad = [&](int mh) {
        __builtin_amdgcn_s_setprio(1);
        #pragma unroll
        for (int ni = 0; ni < 4; ++ni)
            #pragma unroll
            for (int mi = 0; mi < 4; ++mi)
                acc[mh * 4 + mi][ni] =
                    MFMA16(fa[mi], fb[ni], acc[mh * 4 + mi][ni]);
        __builtin_amdgcn_s_setprio(0);
    };

    const int nt = KD / 64;
    stageH(0, 0, 0); stageH(1, 0, 0); stageH(0, 1, 0); stageH(1, 1, 0);
    asm volatile("s_waitcnt vmcnt(4)" ::: "memory");
    BAR();

    for (int t = 0; t < nt; ++t) {
        const int pb = t & 1;
        const bool st = (t + 1 < nt);
        // ---- phase 0: (mh0, kk0); stage A-kh0(t+1) ----
        rdB(pb, 0); rdA(pb, 0, 0);
        if (st) stageH(0, 0, t + 1);
        SB0(); BAR();
        asm volatile("s_waitcnt lgkmcnt(0)" ::: "memory"); SB0();
        quad(0);
        SB0(); BAR();
        // ---- phase 1: (mh1, kk0); stage B-kh0(t+1); vmcnt covers kk1(t) ----
        rdA(pb, 0, 1);
        if (st) stageH(1, 0, t + 1);
        SB0(); BAR();
        asm volatile("s_waitcnt lgkmcnt(0)" ::: "memory"); SB0();
        quad(1);
        SB0();
        if (st) asm volatile("s_waitcnt vmcnt(4)" ::: "memory");
        else    asm volatile("s_waitcnt vmcnt(0)" ::: "memory");
        BAR();
        // ---- phase 2: (mh0, kk1); stage A-kh1(t+1) ----
        rdB(pb, 1); rdA(pb, 1, 0);
        if (st) stageH(0, 1, t + 1);
        SB0(); BAR();
        asm volatile("s_waitcnt lgkmcnt(0)" ::: "memory"); SB0();
        quad(0);
        SB0(); BAR();
        // ---- phase 3: (mh1, kk1); stage B-kh1(t+1); vmcnt covers kh0(t+1) ----
        rdA(pb, 1, 1);
        if (st) stageH(1, 1, t + 1);
        SB0(); BAR();
        asm volatile("s_waitcnt lgkmcnt(0)" ::: "memory"); SB0();
        quad(1);
        SB0();
        asm volatile("s_waitcnt vmcnt(4)" ::: "memory");
        BAR();
    }

    const int m0 = row0 + wr * 128, n0 = col0 + wc * 64;
    if (MODE == 0) {
        const int s = 1 + (col0 >> 10);       // 1:k 2:v, uniform per block
        #pragma unroll
        for (int ni = 0; ni < 4; ++ni) {
            const int col = n0 + ni * 16 + cl;
            const int h = (col & 1023) >> 6, dd = col & 63;
            #pragma unroll
            for (int mi = 0; mi < 8; ++mi)
                #pragma unroll
                for (int r = 0; r < 4; ++r) {
                    const int bt = m0 + mi * 16 + rg * 4 + r;
                    const int bb = bt >> 12, t = bt & (T_ - 1);
                    const size_t bh64 = (size_t)(bb * H_ + h);
                    const signed char sg = (acc[mi][ni][r] >= 0.f) ? 1 : -1;
                    if (s == 1) {
                        K8[(bh64 * T_ + t) * 64 + dd] = sg;   // Kb8 [c][d]
                    } else {
                        const size_t otr = bh64 * ((size_t)T_ * 64)
                                         + (size_t)(t >> 6) * 4096 + dd * 64 + (t & 63);
                        V8[otr] = sg;                         // VbT8 [d][c]
                    }
                }
        }
    } else if (MODE == 2) {
        #pragma unroll
        for (int ni = 0; ni < 4; ++ni) {
            const int col = n0 + ni * 16 + cl;
            const int h = col >> 6, dd = col & 63;
            #pragma unroll
            for (int mi = 0; mi < 8; ++mi)
                #pragma unroll
                for (int r = 0; r < 4; ++r) {
                    const int bt = m0 + mi * 16 + rg * 4 + r;
                    const int bb = bt >> 12, t = bt & (T_ - 1);
                    Oq[((size_t)(bb * H_ + h) * T_ + t) * 64 + dd] =
                        (short)f2bf(acc[mi][ni][r] * 0.125f);
                }
        }
    } else {
        #pragma unroll
        for (int ni = 0; ni < 4; ++ni) {
            const int col = n0 + ni * 16 + cl;
            #pragma unroll
            for (int mi = 0; mi < 8; ++mi)
                #pragma unroll
                for (int r = 0; r < 4; ++r)
                    Yf[(size_t)(m0 + mi * 16 + rg * 4 + r) * D_ + col] =
                        acc[mi][ni][r];
        }
    }
}

// ---------------------------------------------------------------------------
// K2a (MFMA): per chunk, ckvT[dd][kd] = sum_c v[c][dd] k[c][kd] -> CKV8 int8.
// K/V arrive as int8 +-1; converted to bf16 during LDS staging.
// ---------------------------------------------------------------------------
__global__ __launch_bounds__(256)
void k_chunkA(const signed char* __restrict__ Kb8,
              const signed char* __restrict__ VbT8,
              signed char* __restrict__ CKV8)
{
    __shared__ __align__(16) short KTs[4096], VTs[4096];
    __shared__ __align__(16) signed char Cs8[4096];
    const int tid = threadIdx.x;
    const int bh = blockIdx.x >> 6, n = blockIdx.x & 63;
    const size_t kbase = ((size_t)bh * T_ + n * 64) * 64;          // [c][dd]
    const size_t vbase = (size_t)bh * T_ * 64 + (size_t)n * 4096;  // [dd][c]

    {
        const int off = tid * 16;
        // V tile: row dd = off>>6, 16 c-cols -> VTs[dd][c] (swizzled rows)
        int4 vr = *(const int4*)(VbT8 + vbase + off);
        const signed char* vb = (const signed char*)&vr;
        const int vrow = off >> 6, vcb = off & 63;
        #pragma unroll
        for (int jj = 0; jj < 2; ++jj) {
            s16x8 v;
            #pragma unroll
            for (int j = 0; j < 8; ++j)
                v[j] = (vb[jj*8+j] >= 0) ? BF_P1 : BF_M1;
            const int o = (vrow * 128 + (vcb + jj * 8) * 2) ^ ((vrow & 7) << 4);
            *(s16x8*)((char*)VTs + o) = v;
        }
        // K tile: row c = off>>6, 16 dd-cols -> scatter KTs[dd][c]
        int4 kr = *(const int4*)(Kb8 + kbase + off);
        const signed char* kb = (const signed char*)&kr;
        const int c = off >> 6, d0 = off & 63;
        #pragma unroll
        for (int j = 0; j < 16; ++j) {
            const int dd = d0 + j;
            const short sv = (kb[j] >= 0) ? BF_P1 : BF_M1;
            const int o2 = (dd * 128 + c * 2) ^ ((dd & 7) << 4);
            *(short*)((char*)KTs + o2) = sv;
        }
    }
    __syncthreads();

    const int lane = tid & 63, w = tid >> 6;
    const int cl = lane & 15, rg = lane >> 4;
    auto frag = [&](const short* l, int rowbase, int kk) -> s16x8 {
        const int row = rowbase + cl;
        int off = row * 128 + kk * 64 + rg * 16;
        off ^= (row & 7) << 4;
        return *(const s16x8*)((const char*)l + off);
    };

    f32x4 a3[4];
    #pragma unroll
    for (int ni = 0; ni < 4; ++ni) a3[ni] = (f32x4)0.f;
    const s16x8 va0 = frag(VTs, w * 16, 0), va1 = frag(VTs, w * 16, 1);
    #pragma unroll
    for (int ni = 0; ni < 4; ++ni) {
        a3[ni] = MFMA16(va0, frag(KTs, ni * 16, 0), a3[ni]);
        a3[ni] = MFMA16(va1, frag(KTs, ni * 16, 1), a3[ni]);
    }
    #pragma unroll
    for (int ni = 0; ni < 4; ++ni)
        #pragma unroll
        for (int r = 0; r < 4; ++r) {
            const int m = w * 16 + rg * 4 + r;     // dd
            const int c = ni * 16 + cl;            // kd
            Cs8[m * 64 + c] = (signed char)(int)a3[ni][r];
        }
    __syncthreads();
    const size_t c8 = ((size_t)bh * 64 + n) * 4096;
    *(int4*)(CKV8 + c8 + tid * 16) = *(const int4*)(Cs8 + tid * 16);
}

// ---------------------------------------------------------------------------
// K3: integer exclusive scan of CKV8 over chunks -> PB bf16; FM fp32 exact.
// ---------------------------------------------------------------------------
__global__ __launch_bounds__(256)
void k_scan2(const signed char* __restrict__ CKV8, short* __restrict__ PB,
             float* __restrict__ FM, float* __restrict__ FC)
{
    const int bh = blockIdx.x >> 4;
    const int e  = (blockIdx.x & 15) * 256 + threadIdx.x;   // dd*64+kd
    const size_t b8 = (size_t)bh * N_ * 4096 + e;
    const size_t bp = (size_t)bh * N_ * 4096 + e;
    int run = 0;
    #pragma unroll
    for (int nn = 0; nn < 64; ++nn) {
        PB[bp + (size_t)nn * 4096] = (short)f2bf((float)run);
        run += (int)CKV8[b8 + (size_t)nn * 4096];
    }
    FM[(size_t)bh * 4096 + (e & 63) * 64 + (e >> 6)] = (float)run;
    if ((blockIdx.x & 15) == 0 && threadIdx.x == 0) FC[bh] = (float)T_;
}

// ---------------------------------------------------------------------------
// K4 (MFMA, fused): per chunk: S = mask(Q K^T); intra = S V; cross = Q @ P;
// OMb = bf16((intra + cross) / total).  intra never leaves registers.
// ---------------------------------------------------------------------------
__global__ __launch_bounds__(256)
void k_cross3(const short* __restrict__ Qb, const signed char* __restrict__ Kb8,
              const signed char* __restrict__ VbT8, const short* __restrict__ PB,
              short* __restrict__ OMb)
{
    __shared__ __align__(16) short Qs[4096], Ks[4096], VTs[4096], Ps[4096], Ss[4096];
    const int tid = threadIdx.x;
    const int bh = blockIdx.x >> 6, n = blockIdx.x & 63;
    const size_t cbase = ((size_t)bh * T_ + n * 64) * 64;
    const size_t kbase = cbase;                                    // [c][dd]
    const size_t vbase = (size_t)bh * T_ * 64 + (size_t)n * 4096;  // [dd][c]

    auto stage_tile = [&](const short* g, short* l) {
        #pragma unroll
        for (int p = 0; p < 2; ++p) {
            const int off = tid * 16 + p * 4096;
            const int r = off >> 7;
            s16x8 v = *(const s16x8*)(g + (off >> 1));
            *(s16x8*)((char*)l + (off ^ ((r & 7) << 4))) = v;
        }
    };
    stage_tile(Qb + cbase, Qs);
    stage_tile(PB + ((size_t)bh * 64 + n) * 4096, Ps);
    // K, V int8 tiles -> bf16 LDS (direct rows, no transpose needed)
    {
        const int off = tid * 16;
        int4 kr = *(const int4*)(Kb8 + kbase + off);
        const signed char* kb = (const signed char*)&kr;
        int4 vr = *(const int4*)(VbT8 + vbase + off);
        const signed char* vb = (const signed char*)&vr;
        const int row = off >> 6, cb = off & 63;
        #pragma unroll
        for (int jj = 0; jj < 2; ++jj) {
            s16x8 kv, vv;
            #pragma unroll
            for (int j = 0; j < 8; ++j) {
                kv[j] = (kb[jj*8+j] >= 0) ? BF_P1 : BF_M1;
                vv[j] = (vb[jj*8+j] >= 0) ? BF_P1 : BF_M1;
            }
            const int o = (row * 128 + (cb + jj * 8) * 2) ^ ((row & 7) << 4);
            *(s16x8*)((char*)Ks  + o) = kv;
            *(s16x8*)((char*)VTs + o) = vv;
        }
    }
    __syncthreads();

    const int lane = tid & 63, w = tid >> 6;
    const int cl = lane & 15, rg = lane >> 4;
    auto frag = [&](const short* l, int rowbase, int kk) -> s16x8 {
        const int row = rowbase + cl;
        int off = row * 128 + kk * 64 + rg * 16;
        off ^= (row & 7) << 4;
        return *(const s16x8*)((const char*)l + off);
    };

    // phase 1: S = Q K^T (masked) -> Ss (Qs reads complete before barrier)
    const s16x8 qa0 = frag(Qs, w * 16, 0), qa1 = frag(Qs, w * 16, 1);
    {
        f32x4 a1[4];
        #pragma unroll
        for (int ni = 0; ni < 4; ++ni) a1[ni] = (f32x4)0.f;
        #pragma unroll
        for (int ni = 0; ni < 4; ++ni) {
            a1[ni] = MFMA16(qa0, frag(Ks, ni * 16, 0), a1[ni]);
            a1[ni] = MFMA16(qa1, frag(Ks, ni * 16, 1), a1[ni]);
        }
        #pragma unroll
        for (int ni = 0; ni < 4; ++ni)
            #pragma unroll
            for (int r = 0; r < 4; ++r) {
                const int i = w * 16 + rg * 4 + r, j = ni * 16 + cl;
                const float v = (j <= i) ? a1[ni][r] : 0.f;
                const int off = (i * 128 + j * 2) ^ ((i & 7) << 4);
                *(short*)((char*)Ss + off) = (short)f2bf(v);
            }
    }
    __syncthreads();

    // phase 2: intra = S*V; cross = Q*P; combine in f32, /tot, bf16 -> Qs
    {
        f32x4 a2[4], a3[4];
        #pragma unroll
        for (int ni = 0; ni < 4; ++ni) { a2[ni] = (f32x4)0.f; a3[ni] = (f32x4)0.f; }
        const s16x8 sa0 = frag(Ss, w * 16, 0), sa1 = frag(Ss, w * 16, 1);
        #pragma unroll
        for (int ni = 0; ni < 4; ++ni) {
            a2[ni] = MFMA16(sa0, frag(VTs, ni * 16, 0), a2[ni]);
            a2[ni] = MFMA16(sa1, frag(VTs, ni * 16, 1), a2[ni]);
            a3[ni] = MFMA16(qa0, frag(Ps, ni * 16, 0), a3[ni]);
            a3[ni] = MFMA16(qa1, frag(Ps, ni * 16, 1), a3[ni]);
        }
        #pragma unroll
        for (int ni = 0; ni < 4; ++ni)
            #pragma unroll
            for (int r = 0; r < 4; ++r) {
                const int i = w * 16 + rg * 4 + r, j = ni * 16 + cl;
                const float invt = 1.0f / (float)(n * 64 + i + 1);
                const float f = (a2[ni][r] + a3[ni][r]) * invt;
                const int off = (i * 128 + j * 2) ^ ((i & 7) << 4);
                *(short*)((char*)Qs + off) = (short)f2bf(f);
            }
    }
    __syncthreads();

    const int bb = bh >> 4, h = bh & 15;
    #pragma unroll
    for (int p = 0; p < 2; ++p) {
        const int off = tid * 16 + p * 4096;
        const int r = off >> 7;
        const int lo = off ^ ((r & 7) << 4);
        s16x8 v = *(const s16x8*)((char*)Qs + lo);
        const size_t gi = ((size_t)bb * T_ + n * 64 + r) * D_
                        + h * 64 + ((off & 127) >> 1);
        *(s16x8*)(OMb + gi) = v;
    }
}

extern "C" void kernel_launch(void* const* d_in, const int* in_sizes, int n_in,
                              void* d_out, int out_size, void* d_ws, size_t ws_size,
                              hipStream_t stream)
{
    const float* X    = (const float*)d_in[0];
    const float* Wqkv = (const float*)d_in[1];
    const float* Wo   = (const float*)d_in[2];

    float* Y  = (float*)d_out;                       // [B,T,D]
    float* FM = Y + (size_t)B_ * T_ * D_;            // [B,H,64,64]
    float* FC = FM + (size_t)B_ * H_ * HD_ * HD_;    // [B,H,1,1]

    char* ws = (char*)d_ws;
    const size_t Mi = 1048576;
    // Timeline: cvt_split X -> {XS@128, Xb@32}; cvt Wq -> Wqb@208;
    // Q-gemm (Xb,Wqb -> Qb@0); cvt_split Wkv -> WSq@192;
    // KV-gemm (XS,WSq -> Kb8@32, VbT8@48, both over dead Xb);
    // chunkA (Kb8,VbT8 -> CKV8@192 over dead WSq);
    // scan2 -> PB@64; cross3 (Qb,Kb8,VbT8,PB -> OMb@160 over dead XS);
    // cvt Wo -> WoS@210; out-gemm (OMb,WoS -> Y).
    short*       Qb    = (short*)(ws + 0 * Mi);     // 32 MiB
    short*       Xb    = (short*)(ws + 32 * Mi);    // 32 MiB (early)
    signed char* Kb8   = (signed char*)(ws + 32 * Mi);  // 16 MiB (late)
    signed char* VbT8  = (signed char*)(ws + 48 * Mi);  // 16 MiB (late)
    short*       PB    = (short*)(ws + 64 * Mi);    // 32 MiB
    short*       XS    = (short*)(ws + 128 * Mi);   // 64 MiB (early)
    short*       OMb   = (short*)(ws + 160 * Mi);   // 32 MiB (late, over XS hi)
    short*       WSq   = (short*)(ws + 192 * Mi);   //  8 MiB (early)
    signed char* CKV8  = (signed char*)(ws + 192 * Mi); // 16 MiB (late)
    short*       Wqb   = (short*)(ws + 208 * Mi);   //  2 MiB
    short*       WoS   = (short*)(ws + 210 * Mi);   //  2 MiB
    if (ws_size < (size_t)222 * Mi) return;

    dim3 blk(256), blkg(512);
    // X: split (XS) + hi copy (Xb) in one pass
    k_cvt_split<<<dim3(2048), blk, 0, stream>>>(X, XS, Xb, 4194304);
    // Q GEMM first (Xb consumed before Kb8/VbT8 overwrite it)
    k_cvt<<<dim3(512), blk, 0, stream>>>(Wqkv, Wqb, 262144);
    k_gemm<2, 1024, 4><<<dim3(256), blkg, 0, stream>>>(Xb, Wqb, Qb, nullptr, nullptr, nullptr);
    // K/V GEMM: split K=2048, N=2048, int8 sign outputs
    k_cvt_split<<<dim3(1024), blk, 0, stream>>>(Wqkv + (size_t)1024 * 1024, WSq, nullptr, 524288);
    k_gemm<0, 2048, 8><<<dim3(512), blkg, 0, stream>>>(XS, WSq, nullptr, Kb8, VbT8, nullptr);
    // chunk_kv only (needed before scan)
    k_chunkA<<<dim3(4096), blk, 0, stream>>>(Kb8, VbT8, CKV8);
    k_scan2 <<<dim3(1024), blk, 0, stream>>>(CKV8, PB, FM, FC);
    // fused S/intra/cross/normalize
    k_cross3<<<dim3(4096), blk, 0, stream>>>(Qb, Kb8, VbT8, PB, OMb);
    // output GEMM
    k_cvt<<<dim3(512), blk, 0, stream>>>(Wo, WoS, 262144);
    k_gemm<1, 1024, 4><<<dim3(256), blkg, 0, stream>>>(OMb, WoS, nullptr, nullptr, nullptr, Y);
}